// Round 4
// baseline (9030.289 us; speedup 1.0000x reference)
//
#include <hip/hip_runtime.h>
#include <cmath>

// Problem constants (match reference)
constexpr int   B        = 4;
constexpr int   P        = 2048;   // P1 == P2
constexpr int   D        = 64;
constexpr float EPS      = 0.1f;
constexpr float THRESH   = 0.1f;
constexpr int   MAX_ITER = 100;

constexpr float LOG2E   = 1.44269504088896340736f;
constexpr float LN2     = 0.69314718055994530942f;
constexpr float SCALE   = LOG2E / EPS;   // natural -> log2 domain, /eps folded in
constexpr float UNSCALE = EPS * LN2;     // inverse

// ws layout (floats): u2s[8192] | v2s[8192] | uo[8192] | err[128] | errp[1024]
constexpr int WS_U    = 0;
constexpr int WS_V    = 8192;
constexpr int WS_UO   = 16384;
constexpr int WS_ERR  = 24576;
constexpr int WS_ERRP = 24704;
constexpr int WS_FLOATS = 25728;

// ============ prep: C = sum_d (x-y)^2, register-tiled; zero scratch ============
// grid 2048 = B * 32 * 16. Block tile: 64 rows x 128 cols.
__global__ __launch_bounds__(256)
void prep_kernel(const float* __restrict__ x, const float* __restrict__ y,
                 float* __restrict__ out, float* __restrict__ ws)
{
    const int bid = blockIdx.x, tid = threadIdx.x;
    const int bb = bid >> 9, tr = (bid >> 4) & 31, tc = bid & 15;
    const int row0 = tr * 64, col0 = tc * 128;

    if (bid == 0) {
        for (int i = tid; i < WS_FLOATS; i += 256) ws[i] = 0.0f;
        if (tid < B) out[tid] = 0.0f;
    }

    __shared__ float xs[64 * 65];
    __shared__ float ys[128 * 65];
    for (int i = tid; i < 64 * 64; i += 256) {
        int r = i >> 6, d = i & 63;
        xs[r * 65 + d] = x[(size_t)(bb * P + row0 + r) * D + d];
    }
    for (int i = tid; i < 128 * 64; i += 256) {
        int c = i >> 6, d = i & 63;
        ys[c * 65 + d] = y[(size_t)(bb * P + col0 + c) * D + d];
    }
    __syncthreads();

    const int tx = tid & 15, ty = tid >> 4;
    float acc[4][8];
    #pragma unroll
    for (int j = 0; j < 4; ++j)
        #pragma unroll
        for (int i = 0; i < 8; ++i) acc[j][i] = 0.0f;

    #pragma unroll 4
    for (int k = 0; k < 64; ++k) {
        float xa[4], yb[8];
        #pragma unroll
        for (int j = 0; j < 4; ++j) xa[j] = xs[(ty * 4 + j) * 65 + k];
        #pragma unroll
        for (int i = 0; i < 8; ++i) yb[i] = ys[(tx * 8 + i) * 65 + k];
        #pragma unroll
        for (int j = 0; j < 4; ++j)
            #pragma unroll
            for (int i = 0; i < 8; ++i) {
                float d = xa[j] - yb[i];
                acc[j][i] = fmaf(d, d, acc[j][i]);
            }
    }

    float* C_out = out + B + (size_t)B * P * P;
    #pragma unroll
    for (int j = 0; j < 4; ++j) {
        size_t base = (size_t)(bb * P + row0 + ty * 4 + j) * P + col0 + tx * 8;
        ((float4*)&C_out[base])[0] = make_float4(acc[j][0], acc[j][1], acc[j][2], acc[j][3]);
        ((float4*)&C_out[base])[1] = make_float4(acc[j][4], acc[j][5], acc[j][6], acc[j][7]);
    }
}

// ============ fused iteration: u-update + v-column-partials, C read ONCE ============
// grid 1024 = B*256. Block owns 8 rows x 2048 cols. Wave w owns cols [w*512,(w+1)*512)
// for ALL 8 rows (c2[8][2] float4 in regs). u: wave-local LSE + 32-float LDS merge.
// v-partials: pure in-register over the wave's own columns, direct global store.
// NO atomics: per-block |du| goes to errp[bid]; comb sums it.
__global__ __launch_bounds__(256)
void iter_kernel(const float* __restrict__ C, float* __restrict__ part_m,
                 float* __restrict__ part_s, float* __restrict__ ws, int t)
{
    float* u2s  = ws + WS_U;
    float* v2s  = ws + WS_V;
    float* uo   = ws + WS_UO;
    float* err  = ws + WS_ERR;
    float* errp = ws + WS_ERRP;
    if (t > 0 && err[t - 1] < 4.0f * THRESH) return;   // frozen (emulates break)

    const int bid = blockIdx.x, tid = threadIdx.x;
    const int w = tid >> 6, l = tid & 63;
    const int bb = bid >> 8, rc = bid & 255;
    const int baserow = bb * P + rc * 8;               // index into [B*P] arrays

    __shared__ float sm_m[32], sm_s[32];

    const float A = EPS * __logf(1.0f / (float)P + 1e-8f);

    // old v (pre-scaled) for this wave's 2 float4-chunks
    const float4* vv = (const float4*)(v2s + bb * P);
    float4 v4[2];
    #pragma unroll
    for (int k = 0; k < 2; ++k) v4[k] = vv[w * 128 + k * 64 + l];

    // C tile, pre-scaled: c2 = -C/eps*log2e
    float4 c2[8][2];
    #pragma unroll
    for (int j = 0; j < 8; ++j) {
        const float4* Crow = (const float4*)(C + (size_t)(baserow + j) * P);
        #pragma unroll
        for (int k = 0; k < 2; ++k) {
            float4 cc = Crow[w * 128 + k * 64 + l];
            c2[j][k] = make_float4(-SCALE * cc.x, -SCALE * cc.y,
                                   -SCALE * cc.z, -SCALE * cc.w);
        }
    }

    // ---- u phase: wave-local exact LSE over 512 cols ----
    #pragma unroll
    for (int j = 0; j < 8; ++j) {
        float m = -1e30f;
        #pragma unroll
        for (int k = 0; k < 2; ++k)
            m = fmaxf(m, fmaxf(fmaxf(v4[k].x + c2[j][k].x, v4[k].y + c2[j][k].y),
                               fmaxf(v4[k].z + c2[j][k].z, v4[k].w + c2[j][k].w)));
        #pragma unroll
        for (int off = 1; off < 64; off <<= 1) m = fmaxf(m, __shfl_xor(m, off));
        float s = 0.0f;
        #pragma unroll
        for (int k = 0; k < 2; ++k)
            s += exp2f(v4[k].x + c2[j][k].x - m) + exp2f(v4[k].y + c2[j][k].y - m)
               + exp2f(v4[k].z + c2[j][k].z - m) + exp2f(v4[k].w + c2[j][k].w - m);
        #pragma unroll
        for (int off = 1; off < 64; off <<= 1) s += __shfl_xor(s, off);
        if (l == 0) { sm_m[j * 4 + w] = m; sm_s[j * 4 + w] = s; }
    }
    __syncthreads();

    // ---- cross-wave merge (broadcast LDS reads, computed redundantly) ----
    float u2row[8];
    float du_mine = 0.0f;
    #pragma unroll
    for (int j = 0; j < 8; ++j) {
        float M = sm_m[j * 4], S = sm_s[j * 4];
        #pragma unroll
        for (int q = 1; q < 4; ++q) {
            float pm = sm_m[j * 4 + q], ps = sm_s[j * 4 + q];
            float m2 = fmaxf(M, pm);
            S = S * exp2f(M - m2) + ps * exp2f(pm - m2);
            M = m2;
        }
        float u_nat = A - UNSCALE * (M + log2f(S));
        u2row[j] = u_nat * SCALE;
        if (tid == j) {                       // lane j of wave 0 owns row-j bookkeeping
            du_mine = fabsf(u_nat - uo[baserow + j]);
            uo[baserow + j]  = u_nat;
            u2s[baserow + j] = u2row[j];
        }
    }
    if (w == 0) {
        #pragma unroll
        for (int off = 1; off < 64; off <<= 1) du_mine += __shfl_xor(du_mine, off);
        if (l == 0) errp[bid] = du_mine;      // plain store, no atomic
    }

    // ---- v partials over 8 rows (fresh u), in-register, direct store ----
    float4* pmo = (float4*)(part_m + (size_t)(bb * 256 + rc) * P);
    float4* pso = (float4*)(part_s + (size_t)(bb * 256 + rc) * P);
    #pragma unroll
    for (int k = 0; k < 2; ++k) {
        float4 pm, ps;
        #define VPART(COMP)                                            \
        {                                                              \
            float m = -1e30f;                                          \
            _Pragma("unroll")                                          \
            for (int j = 0; j < 8; ++j)                                \
                m = fmaxf(m, u2row[j] + c2[j][k].COMP);                \
            float s = 0.0f;                                            \
            _Pragma("unroll")                                          \
            for (int j = 0; j < 8; ++j)                                \
                s += exp2f(u2row[j] + c2[j][k].COMP - m);              \
            pm.COMP = m; ps.COMP = s;                                  \
        }
        VPART(x) VPART(y) VPART(z) VPART(w)
        #undef VPART
        pmo[w * 128 + k * 64 + l] = pm;
        pso[w * 128 + k * 64 + l] = ps;
    }
}

// ============ combine: fold 256 chunk-partials per column -> v; block 32 sums err ====
__global__ __launch_bounds__(256)
void comb_kernel(const float* __restrict__ part_m, const float* __restrict__ part_s,
                 float* __restrict__ ws, int t)
{
    float* v2s  = ws + WS_V;
    float* err  = ws + WS_ERR;
    float* errp = ws + WS_ERRP;
    if (t > 0 && err[t - 1] < 4.0f * THRESH) return;

    if (blockIdx.x == 32) {                   // err reduction block
        __shared__ float sm[4];
        float s = 0.0f;
        for (int i = threadIdx.x; i < 1024; i += 256) s += errp[i];
        #pragma unroll
        for (int off = 1; off < 64; off <<= 1) s += __shfl_xor(s, off);
        const int w = threadIdx.x >> 6, l = threadIdx.x & 63;
        if (l == 0) sm[w] = s;
        __syncthreads();
        if (threadIdx.x == 0) err[t] = sm[0] + sm[1] + sm[2] + sm[3];
        return;
    }

    const int g = blockIdx.x * 256 + threadIdx.x;      // 0..8191
    const int b = g >> 11, c = g & (P - 1);
    const float* pmb = part_m + (size_t)(b * 256) * P + c;
    const float* psb = part_s + (size_t)(b * 256) * P + c;

    const float A = EPS * __logf(1.0f / (float)P + 1e-8f);

    float M = -1e30f;
    #pragma unroll 8
    for (int q = 0; q < 256; ++q) M = fmaxf(M, pmb[(size_t)q * P]);
    float S = 0.0f;
    #pragma unroll 8
    for (int q = 0; q < 256; ++q)
        S = fmaf(psb[(size_t)q * P], exp2f(pmb[(size_t)q * P] - M), S);

    v2s[g] = (A - UNSCALE * (M + log2f(S))) * SCALE;
}

// ============ epilogue: pi = exp((u+v-C)/eps), cost = sum pi*C ============
__global__ __launch_bounds__(256)
void epi_kernel(float* __restrict__ out, const float* __restrict__ ws)
{
    const float* u2s = ws + WS_U;
    const float* v2s = ws + WS_V;
    float* cost = out;
    float* pi   = out + B;
    const float* C = out + B + (size_t)B * P * P;

    const int bid = blockIdx.x, tid = threadIdx.x;
    const int w = tid >> 6, l = tid & 63;
    const int bb = bid >> 7, rc = bid & 127;
    const int row0 = rc * 16;

    const float4* vv = (const float4*)(v2s + bb * P);
    float4 v4[8];
    #pragma unroll
    for (int k = 0; k < 8; ++k) v4[k] = vv[l + 64 * k];

    float lc = 0.0f;
    #pragma unroll
    for (int j = 0; j < 4; ++j) {
        const int r = row0 + w * 4 + j;
        const float u2 = u2s[bb * P + r];
        const float4* Crow = (const float4*)(C  + (size_t)(bb * P + r) * P);
        float4*       Prow = (float4*)      (pi + (size_t)(bb * P + r) * P);
        #pragma unroll
        for (int k = 0; k < 8; ++k) {
            float4 cc = Crow[l + 64 * k];
            float4 p;
            p.x = exp2f(u2 + v4[k].x - SCALE * cc.x);
            p.y = exp2f(u2 + v4[k].y - SCALE * cc.y);
            p.z = exp2f(u2 + v4[k].z - SCALE * cc.z);
            p.w = exp2f(u2 + v4[k].w - SCALE * cc.w);
            lc = fmaf(p.x, cc.x, lc); lc = fmaf(p.y, cc.y, lc);
            lc = fmaf(p.z, cc.z, lc); lc = fmaf(p.w, cc.w, lc);
            Prow[l + 64 * k] = p;
        }
    }
    #pragma unroll
    for (int off = 1; off < 64; off <<= 1) lc += __shfl_xor(lc, off);
    __shared__ float sm[4];
    if (l == 0) sm[w] = lc;
    __syncthreads();
    if (tid == 0) atomicAdd(&cost[bb], sm[0] + sm[1] + sm[2] + sm[3]);
}

extern "C" void kernel_launch(void* const* d_in, const int* in_sizes, int n_in,
                              void* d_out, int out_size, void* d_ws, size_t ws_size,
                              hipStream_t stream) {
    const float* x = (const float*)d_in[0];
    const float* y = (const float*)d_in[1];
    float* out = (float*)d_out;
    float* ws  = (float*)d_ws;
    const float* C = out + B + (size_t)B * P * P;
    // chunk partials live in the pi region (overwritten by epi): 2 x 8 MB
    float* part_m = out + B;
    float* part_s = part_m + (size_t)1024 * P;

    prep_kernel<<<2048, 256, 0, stream>>>(x, y, out, ws);
    for (int t = 0; t < MAX_ITER; ++t) {
        iter_kernel<<<1024, 256, 0, stream>>>(C, part_m, part_s, ws, t);
        comb_kernel<<<33,   256, 0, stream>>>(part_m, part_s, ws, t);
    }
    epi_kernel<<<512, 256, 0, stream>>>(out, ws);
}

// Round 5
// 8506.505 us; speedup vs baseline: 1.0616x; 1.0616x over previous
//
#include <hip/hip_runtime.h>
#include <cmath>

// Problem constants (match reference)
constexpr int   B        = 4;
constexpr int   P        = 2048;   // P1 == P2
constexpr int   D        = 64;
constexpr float EPS      = 0.1f;
constexpr float THRESH   = 0.1f;
constexpr int   MAX_ITER = 100;

constexpr float LOG2E   = 1.44269504088896340736f;
constexpr float LN2     = 0.69314718055994530942f;
constexpr float SCALE   = LOG2E / EPS;   // natural -> log2 domain, /eps folded in
constexpr float UNSCALE = EPS * LN2;     // inverse

constexpr int NB = 256;                  // persistent grid = #CUs

// ws layout (floats) — zeroed by hipMemsetAsync before the chain:
constexpr int WS_U    = 0;        // u2s[8192] (scaled)
constexpr int WS_V    = 8192;     // v2s[8192] (scaled)
constexpr int WS_ERRP = 16384;    // errp[256]
constexpr int WS_ERR  = 16640;    // err[128]
constexpr int WS_CNT  = 16768;    // barrier counter (int)
constexpr int WS_GEN  = 16769;    // barrier generation (int)
constexpr int WS_FLOATS = 16772;

// ---- software grid barrier (sense-reversing, agent scope) ----
__device__ __forceinline__ void gbar(int* cnt, int* gen) {
    __syncthreads();                       // drains each wave's vmcnt before barrier
    if (threadIdx.x == 0) {
        int g = __hip_atomic_load(gen, __ATOMIC_RELAXED, __HIP_MEMORY_SCOPE_AGENT);
        int a = __hip_atomic_fetch_add(cnt, 1, __ATOMIC_ACQ_REL, __HIP_MEMORY_SCOPE_AGENT);
        if (a == NB - 1) {
            __hip_atomic_store(cnt, 0, __ATOMIC_RELAXED, __HIP_MEMORY_SCOPE_AGENT);
            __hip_atomic_store(gen, g + 1, __ATOMIC_RELEASE, __HIP_MEMORY_SCOPE_AGENT);
        } else {
            unsigned long long t0 = __builtin_amdgcn_s_memrealtime();
            while (__hip_atomic_load(gen, __ATOMIC_ACQUIRE, __HIP_MEMORY_SCOPE_AGENT) == g) {
                __builtin_amdgcn_s_sleep(2);
                if (__builtin_amdgcn_s_memrealtime() - t0 > 100000000ull) break; // ~1s: fail clean, no hang
            }
        }
    }
    __syncthreads();
}

// ============ prep: C = sum_d (x-y)^2, register-tiled ============
__global__ __launch_bounds__(256)
void prep_kernel(const float* __restrict__ x, const float* __restrict__ y,
                 float* __restrict__ out)
{
    const int bid = blockIdx.x, tid = threadIdx.x;
    const int bb = bid >> 9, tr = (bid >> 4) & 31, tc = bid & 15;
    const int row0 = tr * 64, col0 = tc * 128;

    if (bid == 0 && tid < B) out[tid] = 0.0f;          // cost slots

    __shared__ float xs[64 * 65];
    __shared__ float ys[128 * 65];
    for (int i = tid; i < 64 * 64; i += 256) {
        int r = i >> 6, d = i & 63;
        xs[r * 65 + d] = x[(size_t)(bb * P + row0 + r) * D + d];
    }
    for (int i = tid; i < 128 * 64; i += 256) {
        int c = i >> 6, d = i & 63;
        ys[c * 65 + d] = y[(size_t)(bb * P + col0 + c) * D + d];
    }
    __syncthreads();

    const int tx = tid & 15, ty = tid >> 4;
    float acc[4][8];
    #pragma unroll
    for (int j = 0; j < 4; ++j)
        #pragma unroll
        for (int i = 0; i < 8; ++i) acc[j][i] = 0.0f;

    #pragma unroll 4
    for (int k = 0; k < 64; ++k) {
        float xa[4], yb[8];
        #pragma unroll
        for (int j = 0; j < 4; ++j) xa[j] = xs[(ty * 4 + j) * 65 + k];
        #pragma unroll
        for (int i = 0; i < 8; ++i) yb[i] = ys[(tx * 8 + i) * 65 + k];
        #pragma unroll
        for (int j = 0; j < 4; ++j)
            #pragma unroll
            for (int i = 0; i < 8; ++i) {
                float d = xa[j] - yb[i];
                acc[j][i] = fmaf(d, d, acc[j][i]);
            }
    }

    float* C_out = out + B + (size_t)B * P * P;
    #pragma unroll
    for (int j = 0; j < 4; ++j) {
        size_t base = (size_t)(bb * P + row0 + ty * 4 + j) * P + col0 + tx * 8;
        ((float4*)&C_out[base])[0] = make_float4(acc[j][0], acc[j][1], acc[j][2], acc[j][3]);
        ((float4*)&C_out[base])[1] = make_float4(acc[j][4], acc[j][5], acc[j][6], acc[j][7]);
    }
}

// ============ persistent Sinkhorn: C tile lives in registers across all iters ====
// grid 256 x 256, 1 block/CU. Block: batch bb=bid>>6, rows [rc*32, rc*32+32).
// Wave w owns rows w*8..w*8+7; lane l owns cols k*256 + l*4 + c (k<8, c<4) as float4.
// Per iter: in-reg u-LSE -> LDS 4-wave merge of v-partials -> 16KB partial store
// -> grid barrier -> comb (fold 64 chunks/batch-col) -> barrier -> reload v.
__global__ __launch_bounds__(256, 1)
void persist_kernel(const float* __restrict__ C, float* __restrict__ part_m,
                    float* __restrict__ part_s, float* __restrict__ ws)
{
    float* u2s  = ws + WS_U;
    float* v2s  = ws + WS_V;
    float* errp = ws + WS_ERRP;
    float* err  = ws + WS_ERR;
    int*   cnt  = (int*)(ws + WS_CNT);
    int*   gen  = (int*)(ws + WS_GEN);

    const int bid = blockIdx.x, tid = threadIdx.x;
    const int w = tid >> 6, l = tid & 63;
    const int bb = bid >> 6, rc = bid & 63;
    const int row0 = rc * 32;
    const int baserow = bb * P + row0 + w * 8;

    __shared__ float4 lds_m[4 * 512];   // 32 KB: per-wave v-partial m
    __shared__ float4 lds_s[4 * 512];   // 32 KB: per-wave v-partial s
    __shared__ float  sm_cm[256], sm_cs[256];
    __shared__ float  sm4[4];

    const float A = EPS * __logf(1.0f / (float)P + 1e-8f);

    // ---- load C tile into registers, pre-scaled: c2 = -C/eps*log2e ----
    float4 c2[8][8];
    #pragma unroll
    for (int r = 0; r < 8; ++r) {
        const float4* Crow = (const float4*)(C + (size_t)(baserow + r) * P);
        #pragma unroll
        for (int k = 0; k < 8; ++k) {
            float4 cc = Crow[k * 64 + l];
            c2[r][k] = make_float4(-SCALE * cc.x, -SCALE * cc.y,
                                   -SCALE * cc.z, -SCALE * cc.w);
        }
    }

    // duals (registers; uo8 = previous natural u for err)
    float4 v4[8];
    const float4* vvB = (const float4*)(v2s + bb * P);
    #pragma unroll
    for (int k = 0; k < 8; ++k) v4[k] = vvB[k * 64 + l];   // zeros (memset)
    float u2row[8], uo8[8];
    #pragma unroll
    for (int r = 0; r < 8; ++r) uo8[r] = 0.0f;

    #pragma clang loop unroll(disable)
    for (int it = 0; it < MAX_ITER; ++it) {
        // ---- u phase: exact LSE over 2048 cols per row (in-wave) ----
        float du = 0.0f;
        #pragma unroll
        for (int r = 0; r < 8; ++r) {
            float m = -1e30f;
            #pragma unroll
            for (int k = 0; k < 8; ++k) {
                m = fmaxf(m, fmaxf(fmaxf(v4[k].x + c2[r][k].x, v4[k].y + c2[r][k].y),
                                   fmaxf(v4[k].z + c2[r][k].z, v4[k].w + c2[r][k].w)));
            }
            #pragma unroll
            for (int off = 1; off < 64; off <<= 1) m = fmaxf(m, __shfl_xor(m, off));
            float s = 0.0f;
            #pragma unroll
            for (int k = 0; k < 8; ++k) {
                s += exp2f(v4[k].x + c2[r][k].x - m) + exp2f(v4[k].y + c2[r][k].y - m)
                   + exp2f(v4[k].z + c2[r][k].z - m) + exp2f(v4[k].w + c2[r][k].w - m);
            }
            #pragma unroll
            for (int off = 1; off < 64; off <<= 1) s += __shfl_xor(s, off);
            float u_nat = A - UNSCALE * (m + log2f(s));
            du += fabsf(u_nat - uo8[r]);
            uo8[r]   = u_nat;
            u2row[r] = u_nat * SCALE;
        }
        if (l == 0) sm4[w] = du;        // du identical across lanes

        // ---- v partials over this wave's 8 rows -> LDS ----
        #pragma unroll
        for (int k = 0; k < 8; ++k) {
            float4 pm = make_float4(-1e30f, -1e30f, -1e30f, -1e30f), ps;
            #pragma unroll
            for (int r = 0; r < 8; ++r) {
                pm.x = fmaxf(pm.x, u2row[r] + c2[r][k].x);
                pm.y = fmaxf(pm.y, u2row[r] + c2[r][k].y);
                pm.z = fmaxf(pm.z, u2row[r] + c2[r][k].z);
                pm.w = fmaxf(pm.w, u2row[r] + c2[r][k].w);
            }
            ps = make_float4(0.f, 0.f, 0.f, 0.f);
            #pragma unroll
            for (int r = 0; r < 8; ++r) {
                ps.x += exp2f(u2row[r] + c2[r][k].x - pm.x);
                ps.y += exp2f(u2row[r] + c2[r][k].y - pm.y);
                ps.z += exp2f(u2row[r] + c2[r][k].z - pm.z);
                ps.w += exp2f(u2row[r] + c2[r][k].w - pm.w);
            }
            lds_m[w * 512 + k * 64 + l] = pm;
            lds_s[w * 512 + k * 64 + l] = ps;
        }
        __syncthreads();

        // ---- 4-wave merge -> block partial (2048 cols, 16 KB) ----
        {
            float4* pmo = (float4*)(part_m + (size_t)bid * P);
            float4* pso = (float4*)(part_s + (size_t)bid * P);
            #pragma unroll
            for (int h = 0; h < 2; ++h) {
                const int j4 = tid * 2 + h;            // float4-col 0..511
                float4 M = lds_m[j4], S = lds_s[j4];
                #pragma unroll
                for (int q = 1; q < 4; ++q) {
                    float4 pm = lds_m[q * 512 + j4], ps = lds_s[q * 512 + j4];
                    float m2;
                    m2 = fmaxf(M.x, pm.x); S.x = S.x * exp2f(M.x - m2) + ps.x * exp2f(pm.x - m2); M.x = m2;
                    m2 = fmaxf(M.y, pm.y); S.y = S.y * exp2f(M.y - m2) + ps.y * exp2f(pm.y - m2); M.y = m2;
                    m2 = fmaxf(M.z, pm.z); S.z = S.z * exp2f(M.z - m2) + ps.z * exp2f(pm.z - m2); M.z = m2;
                    m2 = fmaxf(M.w, pm.w); S.w = S.w * exp2f(M.w - m2) + ps.w * exp2f(pm.w - m2); M.w = m2;
                }
                pmo[j4] = M;
                pso[j4] = S;
            }
            if (tid == 0) errp[bid] = sm4[0] + sm4[1] + sm4[2] + sm4[3];
        }

        gbar(cnt, gen);   // partials + errp globally visible

        // ---- comb: fold 64 chunk-partials per column -> v (32 cols/block) ----
        {
            const int jl = tid & 31, p = tid >> 5;     // 8 chunks each
            const int gcol = bid * 32 + jl;            // global col 0..8191
            const int cb = gcol >> 11, cj = gcol & (P - 1);
            const float* pmB = part_m + (size_t)(cb * 64) * P + cj;
            const float* psB = part_s + (size_t)(cb * 64) * P + cj;
            float M = -1e30f, S = 0.0f;
            #pragma unroll
            for (int q = 0; q < 8; ++q) {
                const size_t off = (size_t)(p * 8 + q) * P;
                float pm = pmB[off], ps = psB[off];
                float m2 = fmaxf(M, pm);
                S = S * exp2f(M - m2) + ps * exp2f(pm - m2);
                M = m2;
            }
            sm_cm[tid] = M;
            sm_cs[tid] = S;
            __syncthreads();
            if (p == 0) {                              // tid<32 folds 8 entries
                #pragma unroll
                for (int q = 1; q < 8; ++q) {
                    float pm = sm_cm[jl + 32 * q], ps = sm_cs[jl + 32 * q];
                    float m2 = fmaxf(M, pm);
                    S = S * exp2f(M - m2) + ps * exp2f(pm - m2);
                    M = m2;
                }
                v2s[gcol] = (A - UNSCALE * (M + log2f(S))) * SCALE;
            }
            if (bid == 0) {                            // err reduction
                float e = errp[tid];
                #pragma unroll
                for (int off = 1; off < 64; off <<= 1) e += __shfl_xor(e, off);
                if (l == 0) sm4[w] = e;
                __syncthreads();
                if (tid == 0) err[it] = sm4[0] + sm4[1] + sm4[2] + sm4[3];
            }
        }

        gbar(cnt, gen);   // v2s + err visible; L1/L2 acquired fresh

        // ---- reload v, uniform early break (emulates reference freeze) ----
        #pragma unroll
        for (int k = 0; k < 8; ++k) v4[k] = vvB[k * 64 + l];
        float errv = err[it];
        if (errv * 0.25f < THRESH) break;
    }

    // final duals for the epilogue
    if (l == 0) {
        #pragma unroll
        for (int r = 0; r < 8; ++r) u2s[baserow + r] = u2row[r];
    }
}

// ============ epilogue: pi = exp((u+v-C)/eps), cost = sum pi*C ============
__global__ __launch_bounds__(256)
void epi_kernel(float* __restrict__ out, const float* __restrict__ ws)
{
    const float* u2s = ws + WS_U;
    const float* v2s = ws + WS_V;
    float* cost = out;
    float* pi   = out + B;
    const float* C = out + B + (size_t)B * P * P;

    const int bid = blockIdx.x, tid = threadIdx.x;
    const int w = tid >> 6, l = tid & 63;
    const int bb = bid >> 7, rc = bid & 127;
    const int row0 = rc * 16;

    const float4* vv = (const float4*)(v2s + bb * P);
    float4 v4[8];
    #pragma unroll
    for (int k = 0; k < 8; ++k) v4[k] = vv[l + 64 * k];

    float lc = 0.0f;
    #pragma unroll
    for (int j = 0; j < 4; ++j) {
        const int r = row0 + w * 4 + j;
        const float u2 = u2s[bb * P + r];
        const float4* Crow = (const float4*)(C  + (size_t)(bb * P + r) * P);
        float4*       Prow = (float4*)      (pi + (size_t)(bb * P + r) * P);
        #pragma unroll
        for (int k = 0; k < 8; ++k) {
            float4 cc = Crow[l + 64 * k];
            float4 p;
            p.x = exp2f(u2 + v4[k].x - SCALE * cc.x);
            p.y = exp2f(u2 + v4[k].y - SCALE * cc.y);
            p.z = exp2f(u2 + v4[k].z - SCALE * cc.z);
            p.w = exp2f(u2 + v4[k].w - SCALE * cc.w);
            lc = fmaf(p.x, cc.x, lc); lc = fmaf(p.y, cc.y, lc);
            lc = fmaf(p.z, cc.z, lc); lc = fmaf(p.w, cc.w, lc);
            Prow[l + 64 * k] = p;
        }
    }
    #pragma unroll
    for (int off = 1; off < 64; off <<= 1) lc += __shfl_xor(lc, off);
    __shared__ float sm[4];
    if (l == 0) sm[w] = lc;
    __syncthreads();
    if (tid == 0) atomicAdd(&cost[bb], sm[0] + sm[1] + sm[2] + sm[3]);
}

extern "C" void kernel_launch(void* const* d_in, const int* in_sizes, int n_in,
                              void* d_out, int out_size, void* d_ws, size_t ws_size,
                              hipStream_t stream) {
    const float* x = (const float*)d_in[0];
    const float* y = (const float*)d_in[1];
    float* out = (float*)d_out;
    float* ws  = (float*)d_ws;
    const float* C = out + B + (size_t)B * P * P;
    // chunk partials live in the pi region (overwritten by epi): 2 x 2 MB
    float* part_m = out + B;
    float* part_s = part_m + (size_t)NB * P;

    hipMemsetAsync(d_ws, 0, WS_FLOATS * sizeof(float), stream);  // duals/err/barrier = 0
    prep_kernel<<<2048, 256, 0, stream>>>(x, y, out);
    persist_kernel<<<NB, 256, 0, stream>>>(C, part_m, part_s, ws);
    epi_kernel<<<512, 256, 0, stream>>>(out, ws);
}